// Round 3
// baseline (273.250 us; speedup 1.0000x reference)
//
#include <hip/hip_runtime.h>

#define DH 1024
#define FH 2752
#define NE 8
#define NT 1024
#define BM 256

typedef unsigned short u16;
typedef __bf16 bf16x8 __attribute__((ext_vector_type(8)));
typedef u16 u16x8 __attribute__((ext_vector_type(8)));
typedef float f32x4 __attribute__((ext_vector_type(4)));

__device__ __forceinline__ u16 f2bf(float f) {
  unsigned int u = __float_as_uint(f);
  unsigned int r = (u + 0x7fffu + ((u >> 16) & 1u)) >> 16;
  return (u16)r;
}
__device__ __forceinline__ float bf2f(u16 b) {
  return __uint_as_float(((unsigned int)b) << 16);
}
__device__ __forceinline__ bf16x8 as_bf(int4 v) {
  union { int4 i; bf16x8 b; } u; u.i = v; return u.b;
}

// ---------------- 1. gating ----------------
__global__ void gate_kernel(const float* __restrict__ x,
                            const float* __restrict__ Ws,
                            const float* __restrict__ bs,
                            u16* __restrict__ xb,
                            int* __restrict__ tki,
                            float* __restrict__ tkw) {
  int gtid = blockIdx.x * blockDim.x + threadIdx.x;
  int t = gtid >> 6;
  int lane = gtid & 63;
  if (t >= NT) return;
  const float* xr = x + (size_t)t * DH;
  float acc[NE];
#pragma unroll
  for (int e = 0; e < NE; ++e) acc[e] = 0.f;
  for (int d = lane; d < DH; d += 64) {
    float xv = xr[d];
    xb[(size_t)t * DH + d] = f2bf(xv);
    const float4* wr = (const float4*)(Ws + (size_t)d * NE);
    float4 w0 = wr[0], w1 = wr[1];
    acc[0] += xv * w0.x; acc[1] += xv * w0.y;
    acc[2] += xv * w0.z; acc[3] += xv * w0.w;
    acc[4] += xv * w1.x; acc[5] += xv * w1.y;
    acc[6] += xv * w1.z; acc[7] += xv * w1.w;
  }
#pragma unroll
  for (int e = 0; e < NE; ++e) {
#pragma unroll
    for (int off = 32; off > 0; off >>= 1)
      acc[e] += __shfl_xor(acc[e], off);
  }
  if (lane == 0) {
    float l[NE];
#pragma unroll
    for (int e = 0; e < NE; ++e) l[e] = acc[e] + bs[e];
    int i0 = 0;
#pragma unroll
    for (int e = 1; e < NE; ++e) if (l[e] > l[i0]) i0 = e;
    int i1 = (i0 == 0) ? 1 : 0;
#pragma unroll
    for (int e = 0; e < NE; ++e) if (e != i0 && l[e] > l[i1]) i1 = e;
    float e1 = __expf(l[i1] - l[i0]);
    float denom = 1.f + e1;
    tki[t*2]   = i0; tki[t*2+1] = i1;
    tkw[t*2]   = 1.f / denom;
    tkw[t*2+1] = e1 / denom;
  }
}

// ---------------- 2. expert grouping ----------------
__global__ void group_kernel(const int* __restrict__ tki,
                             int* __restrict__ offs,
                             int* __restrict__ rtok,
                             int* __restrict__ posf) {
  __shared__ int cnt[NE];
  __shared__ int run[NE];
  int tid = threadIdx.x;
  if (tid < NE) cnt[tid] = 0;
  __syncthreads();
  for (int t = tid; t < NT; t += blockDim.x) {
    atomicAdd(&cnt[tki[t*2]], 1);
    atomicAdd(&cnt[tki[t*2+1]], 1);
  }
  __syncthreads();
  if (tid == 0) {
    int r = 0;
    for (int e = 0; e < NE; ++e) { offs[e] = r; run[e] = r; r += cnt[e]; }
    offs[NE] = r;
  }
  __syncthreads();
  for (int t = tid; t < NT; t += blockDim.x) {
    for (int k = 0; k < 2; ++k) {
      int e = tki[t*2+k];
      int p = atomicAdd(&run[e], 1);
      rtok[p] = t;
      posf[t*2+k] = p;
    }
  }
}

// ---------------- 3. fused gate+up+SwiGLU, no-LDS streaming GEMM ----------------
// BM=256 x BN=32, 4 waves, each wave owns 64 rows. K-step 32, 2-stage reg pipeline.
// A (tokens, bf16) and W (fp32, converted in-reg) both load straight to VGPRs.
#define GU_LOAD(ST, KT)                                                        \
  {                                                                            \
    int kb = (KT) * 32;                                                        \
    _Pragma("unroll") for (int mf = 0; mf < 4; ++mf)                           \
      A##ST[mf] = *(const int4*)(aptr[mf] + kb);                               \
    _Pragma("unroll") for (int nf = 0; nf < 2; ++nf)                           \
      _Pragma("unroll") for (int j = 0; j < 8; ++j) {                          \
        Bg##ST[nf][j] = gcol[(kb + j) * FH + nf * 16];                         \
        Bu##ST[nf][j] = ucol[(kb + j) * FH + nf * 16];                         \
      }                                                                        \
  }

#define GU_COMPUTE(ST)                                                         \
  {                                                                            \
    _Pragma("unroll") for (int nf = 0; nf < 2; ++nf) {                         \
      bf16x8 fg, fu;                                                           \
      _Pragma("unroll") for (int j = 0; j < 8; ++j) {                          \
        fg[j] = (__bf16)Bg##ST[nf][j];                                         \
        fu[j] = (__bf16)Bu##ST[nf][j];                                         \
      }                                                                        \
      _Pragma("unroll") for (int mf = 0; mf < 4; ++mf) {                       \
        bf16x8 av = as_bf(A##ST[mf]);                                          \
        accg[mf][nf] = __builtin_amdgcn_mfma_f32_16x16x32_bf16(av, fg, accg[mf][nf], 0,0,0); \
        accu[mf][nf] = __builtin_amdgcn_mfma_f32_16x16x32_bf16(av, fu, accu[mf][nf], 0,0,0); \
      }                                                                        \
    }                                                                          \
  }

__global__ __launch_bounds__(256, 2)
void gu_kernel(const u16* __restrict__ xb,
               const float* __restrict__ Wg,
               const float* __restrict__ Wu,
               u16* __restrict__ hbuf,
               const int* __restrict__ offs,
               const int* __restrict__ rtok) {
  int e  = blockIdx.z;
  int mt = blockIdx.y;
  int nt = blockIdx.x;
  int off0 = offs[e];
  int cnt  = offs[e+1] - off0;
  if (cnt <= 0 || mt * BM >= cnt) return;
  int p0 = off0 + mt * BM;
  int rmax = cnt - mt * BM - 1;
  int n0 = nt * 32;
  int tid = threadIdx.x;
  int lane = tid & 63, wv = tid >> 6;
  int kg = (lane >> 4) * 8;
  int nl = lane & 15;

  const u16* aptr[4];
#pragma unroll
  for (int mf = 0; mf < 4; ++mf) {
    int lrow = wv*64 + nl + mf*16;
    int tok = rtok[p0 + (lrow > rmax ? rmax : lrow)];
    aptr[mf] = xb + (size_t)tok * DH + kg;
  }
  // per-lane W column pointers: fixed col = n0+nl, fixed k-group offset kg
  const float* gcol = Wg + (size_t)e * DH * FH + (size_t)kg * FH + n0 + nl;
  const float* ucol = Wu + (size_t)e * DH * FH + (size_t)kg * FH + n0 + nl;

  f32x4 accg[4][2], accu[4][2];
#pragma unroll
  for (int mf = 0; mf < 4; ++mf)
#pragma unroll
    for (int nf = 0; nf < 2; ++nf) {
      accg[mf][nf] = f32x4{0.f,0.f,0.f,0.f};
      accu[mf][nf] = f32x4{0.f,0.f,0.f,0.f};
    }

  int4 A0[4], A1[4];
  float Bg0[2][8], Bg1[2][8], Bu0[2][8], Bu1[2][8];

  GU_LOAD(0, 0);
  for (int t = 0; t < 32; t += 2) {
    GU_LOAD(1, t+1);
    GU_COMPUTE(0);
    if (t + 2 < 32) GU_LOAD(0, t+2);
    GU_COMPUTE(1);
  }

  // epilogue: h = silu(g)*u, bf16
#pragma unroll
  for (int mf = 0; mf < 4; ++mf) {
    int lr0 = wv*64 + (lane >> 4)*4 + mf*16;
#pragma unroll
    for (int nf = 0; nf < 2; ++nf) {
      int col = n0 + nf*16 + nl;
#pragma unroll
      for (int q = 0; q < 4; ++q) {
        int lrow = lr0 + q;
        if (lrow <= rmax) {
          float g = accg[mf][nf][q], u = accu[mf][nf][q];
          float s = g / (1.f + __expf(-g));
          hbuf[(size_t)(p0 + lrow) * FH + col] = f2bf(s * u);
        }
      }
    }
  }
}

// ---------------- 4. down projection, no-LDS streaming, K-split=2 ----------------
#define DN_LOAD(ST, KT)                                                        \
  {                                                                            \
    int kb = (KT) * 32;                                                        \
    _Pragma("unroll") for (int mf = 0; mf < 4; ++mf)                           \
      A##ST[mf] = *(const int4*)(aptr[mf] + kb);                               \
    _Pragma("unroll") for (int nf = 0; nf < 2; ++nf)                           \
      _Pragma("unroll") for (int j = 0; j < 8; ++j)                            \
        Bd##ST[nf][j] = dcol[(kb + j) * DH + nf * 16];                         \
  }

#define DN_COMPUTE(ST)                                                         \
  {                                                                            \
    _Pragma("unroll") for (int nf = 0; nf < 2; ++nf) {                         \
      bf16x8 fd;                                                               \
      _Pragma("unroll") for (int j = 0; j < 8; ++j)                            \
        fd[j] = (__bf16)Bd##ST[nf][j];                                         \
      _Pragma("unroll") for (int mf = 0; mf < 4; ++mf) {                       \
        bf16x8 av = as_bf(A##ST[mf]);                                          \
        acc[mf][nf] = __builtin_amdgcn_mfma_f32_16x16x32_bf16(av, fd, acc[mf][nf], 0,0,0); \
      }                                                                        \
    }                                                                          \
  }

__global__ __launch_bounds__(256, 2)
void dn_kernel(const u16* __restrict__ hb,
               const float* __restrict__ Wd,
               float* __restrict__ y,
               const int* __restrict__ offs) {
  int e  = blockIdx.z;
  int mt = blockIdx.y;
  int bx = blockIdx.x;
  int nt = bx & 31;
  int ks = bx >> 5;
  int kt0 = ks * 1376;            // 2752/2; 1376 = 43 * 32
  int off0 = offs[e];
  int cnt  = offs[e+1] - off0;
  if (cnt <= 0 || mt * BM >= cnt) return;
  int p0 = off0 + mt * BM;
  int rmax = cnt - mt * BM - 1;
  int n0 = nt * 32;
  int tid = threadIdx.x;
  int lane = tid & 63, wv = tid >> 6;
  int kg = (lane >> 4) * 8;
  int nl = lane & 15;

  const u16* aptr[4];
#pragma unroll
  for (int mf = 0; mf < 4; ++mf) {
    int lrow = wv*64 + nl + mf*16;
    int arow = p0 + (lrow > rmax ? rmax : lrow);
    aptr[mf] = hb + (size_t)arow * FH + kt0 + kg;
  }
  const float* dcol = Wd + (size_t)e * FH * DH + (size_t)(kt0 + kg) * DH + n0 + nl;

  f32x4 acc[4][2];
#pragma unroll
  for (int mf = 0; mf < 4; ++mf)
#pragma unroll
    for (int nf = 0; nf < 2; ++nf)
      acc[mf][nf] = f32x4{0.f,0.f,0.f,0.f};

  int4 A0[4], A1[4];
  float Bd0[2][8], Bd1[2][8];

  DN_LOAD(0, 0);
  int t = 0;
  for (; t + 2 <= 43; t += 2) {
    DN_LOAD(1, t+1);
    DN_COMPUTE(0);
    if (t + 2 < 43) DN_LOAD(0, t+2);
    DN_COMPUTE(1);
  }
  DN_COMPUTE(0);   // iter 42 (loaded in last loop pass)

  float* yout = y + (size_t)ks * 2048 * DH;
#pragma unroll
  for (int mf = 0; mf < 4; ++mf) {
    int lr0 = wv*64 + (lane >> 4)*4 + mf*16;
#pragma unroll
    for (int nf = 0; nf < 2; ++nf) {
      int col = n0 + nf*16 + nl;
#pragma unroll
      for (int q = 0; q < 4; ++q) {
        int lrow = lr0 + q;
        if (lrow <= rmax)
          yout[(size_t)(p0 + lrow) * DH + col] = acc[mf][nf][q];
      }
    }
  }
}

// ---------------- 5. combine ----------------
__global__ void combine_kernel(const float* __restrict__ y,
                               const float* __restrict__ tkw,
                               const int* __restrict__ posf,
                               float* __restrict__ out) {
  int t = blockIdx.x;
  int d = threadIdx.x;
  const float* y1 = y + (size_t)2048 * DH;
  int pa = posf[t*2], pb = posf[t*2+1];
  float wa = tkw[t*2], wb = tkw[t*2+1];
  f32x4 a0 = ((const f32x4*)(y  + (size_t)pa * DH))[d];
  f32x4 a1 = ((const f32x4*)(y1 + (size_t)pa * DH))[d];
  f32x4 b0 = ((const f32x4*)(y  + (size_t)pb * DH))[d];
  f32x4 b1 = ((const f32x4*)(y1 + (size_t)pb * DH))[d];
  f32x4 o;
#pragma unroll
  for (int i = 0; i < 4; ++i)
    o[i] = wa*(a0[i]+a1[i]) + wb*(b0[i]+b1[i]);
  ((f32x4*)(out + (size_t)t * DH))[d] = o;
}

extern "C" void kernel_launch(void* const* d_in, const int* in_sizes, int n_in,
                              void* d_out, int out_size, void* d_ws, size_t ws_size,
                              hipStream_t stream) {
  const float* x  = (const float*)d_in[0];
  const float* Ws = (const float*)d_in[1];
  const float* bs = (const float*)d_in[2];
  const float* Wg = (const float*)d_in[3];
  const float* Wu = (const float*)d_in[4];
  const float* Wd = (const float*)d_in[5];
  float* out = (float*)d_out;
  char* ws = (char*)d_ws;

  int*   tki  = (int*)  (ws + 0);
  float* tkw  = (float*)(ws + 8192);
  int*   offs = (int*)  (ws + 16384);
  int*   posf = (int*)  (ws + 20480);
  int*   rtok = (int*)  (ws + 28672);
  u16*   xb   = (u16*)  (ws + 36864);                 // 2 MB
  char*  base2 = ws + 36864 + 2097152;
  u16*   hbuf = (u16*)(base2);                        // 2048*2752 bf16 = 11.27 MB
  float* yws  = (float*)(base2 + 11272192);           // 2 * 2048*1024 f32 = 16 MB

  gate_kernel<<<256, 256, 0, stream>>>(x, Ws, bs, xb, tki, tkw);
  group_kernel<<<1, 256, 0, stream>>>(tki, offs, rtok, posf);
  gu_kernel<<<dim3(FH/32, 4, NE), 256, 0, stream>>>(xb, Wg, Wu, hbuf, offs, rtok);
  dn_kernel<<<dim3(64, 4, NE), 256, 0, stream>>>(hbuf, Wd, yws, offs);
  combine_kernel<<<NT, 256, 0, stream>>>(yws, tkw, posf, out);
}

// Round 4
// 190.977 us; speedup vs baseline: 1.4308x; 1.4308x over previous
//
#include <hip/hip_runtime.h>

#define DH 1024
#define FH 2752
#define NE 8
#define NT 1024
#define BM 256

typedef unsigned short u16;
typedef __bf16 bf16x8 __attribute__((ext_vector_type(8)));
typedef u16 u16x8 __attribute__((ext_vector_type(8)));
typedef float f32x4 __attribute__((ext_vector_type(4)));

__device__ __forceinline__ u16 f2bf(float f) {
  unsigned int u = __float_as_uint(f);
  unsigned int r = (u + 0x7fffu + ((u >> 16) & 1u)) >> 16;
  return (u16)r;
}
__device__ __forceinline__ bf16x8 as_bf(int4 v) {
  union { int4 i; bf16x8 b; } u; u.i = v; return u.b;
}
__device__ __forceinline__ bf16x8 as_bfu(u16x8 v) {
  union { u16x8 u; bf16x8 b; } x; x.u = v; return x.b;
}

// raw barrier: lgkm drain for LDS visibility, NO vmcnt drain (loads stay in flight)
#define BAR()                                                   \
  do {                                                          \
    asm volatile("s_waitcnt lgkmcnt(0)" ::: "memory");          \
    __builtin_amdgcn_s_barrier();                               \
    asm volatile("" ::: "memory");                              \
  } while (0)

// ---------------- 1. gating ----------------
__global__ void gate_kernel(const float* __restrict__ x,
                            const float* __restrict__ Ws,
                            const float* __restrict__ bs,
                            u16* __restrict__ xb,
                            int* __restrict__ tki,
                            float* __restrict__ tkw) {
  int gtid = blockIdx.x * blockDim.x + threadIdx.x;
  int t = gtid >> 6;
  int lane = gtid & 63;
  if (t >= NT) return;
  const float* xr = x + (size_t)t * DH;
  float acc[NE];
#pragma unroll
  for (int e = 0; e < NE; ++e) acc[e] = 0.f;
  for (int d = lane; d < DH; d += 64) {
    float xv = xr[d];
    xb[(size_t)t * DH + d] = f2bf(xv);
    const float4* wr = (const float4*)(Ws + (size_t)d * NE);
    float4 w0 = wr[0], w1 = wr[1];
    acc[0] += xv * w0.x; acc[1] += xv * w0.y;
    acc[2] += xv * w0.z; acc[3] += xv * w0.w;
    acc[4] += xv * w1.x; acc[5] += xv * w1.y;
    acc[6] += xv * w1.z; acc[7] += xv * w1.w;
  }
#pragma unroll
  for (int e = 0; e < NE; ++e) {
#pragma unroll
    for (int off = 32; off > 0; off >>= 1)
      acc[e] += __shfl_xor(acc[e], off);
  }
  if (lane == 0) {
    float l[NE];
#pragma unroll
    for (int e = 0; e < NE; ++e) l[e] = acc[e] + bs[e];
    int i0 = 0;
#pragma unroll
    for (int e = 1; e < NE; ++e) if (l[e] > l[i0]) i0 = e;
    int i1 = (i0 == 0) ? 1 : 0;
#pragma unroll
    for (int e = 0; e < NE; ++e) if (e != i0 && l[e] > l[i1]) i1 = e;
    float e1 = __expf(l[i1] - l[i0]);
    float denom = 1.f + e1;
    tki[t*2]   = i0; tki[t*2+1] = i1;
    tkw[t*2]   = 1.f / denom;
    tkw[t*2+1] = e1 / denom;
  }
}

// ---------------- 2. expert grouping ----------------
__global__ void group_kernel(const int* __restrict__ tki,
                             int* __restrict__ offs,
                             int* __restrict__ rtok,
                             int* __restrict__ posf) {
  __shared__ int cnt[NE];
  __shared__ int run[NE];
  int tid = threadIdx.x;
  if (tid < NE) cnt[tid] = 0;
  __syncthreads();
  for (int t = tid; t < NT; t += blockDim.x) {
    atomicAdd(&cnt[tki[t*2]], 1);
    atomicAdd(&cnt[tki[t*2+1]], 1);
  }
  __syncthreads();
  if (tid == 0) {
    int r = 0;
    for (int e = 0; e < NE; ++e) { offs[e] = r; run[e] = r; r += cnt[e]; }
    offs[NE] = r;
  }
  __syncthreads();
  for (int t = tid; t < NT; t += blockDim.x) {
    for (int k = 0; k < 2; ++k) {
      int e = tki[t*2+k];
      int p = atomicAdd(&run[e], 1);
      rtok[p] = t;
      posf[t*2+k] = p;
    }
  }
}

// ---------------- 3. fused gate+up+SwiGLU GEMM ----------------
// BM=256 x BN=32, BK=64, 4 waves. A global->reg (1-deep prefetch),
// B f32->bf16 reg-staged to double-buffered LDS (2-deep prefetch),
// raw barriers (no vmcnt drain).
#define GU_LOADA(AS, KT)                                                     \
  { _Pragma("unroll") for (int mf = 0; mf < 4; ++mf) {                       \
      AS[mf][0] = *(const int4*)(aptr[mf] + (KT)*64);                        \
      AS[mf][1] = *(const int4*)(aptr[mf] + (KT)*64 + 32);                   \
  } }

#define GU_LOADB(BS, KT)                                                     \
  { const float* gp_ = gsrc + (size_t)(KT)*64*FH;                            \
    const float* up_ = usrc + (size_t)(KT)*64*FH;                            \
    _Pragma("unroll") for (int r_ = 0; r_ < 4; ++r_) {                       \
      BS##g[r_] = *(const float2*)(gp_ + (size_t)r_*FH);                     \
      BS##u[r_] = *(const float2*)(up_ + (size_t)r_*FH);                     \
  } }

#define GU_WRITEB(BS, BUF)                                                   \
  { _Pragma("unroll") for (int j_ = 0; j_ < 2; ++j_) {                       \
      union { u16 s[4]; uint2 v; } pg_, pu_;                                 \
      _Pragma("unroll") for (int r_ = 0; r_ < 4; ++r_) {                     \
        pg_.s[r_] = f2bf(j_ ? BS##g[r_].y : BS##g[r_].x);                    \
        pu_.s[r_] = f2bf(j_ ? BS##u[r_].y : BS##u[r_].x);                    \
      }                                                                      \
      *(uint2*)&bg_sm[BUF][2*cc + j_][4*gg] = pg_.v;                         \
      *(uint2*)&bu_sm[BUF][2*cc + j_][4*gg] = pu_.v;                         \
  } }

#define GU_READF(CUR)                                                        \
  { _Pragma("unroll") for (int h_ = 0; h_ < 2; ++h_) {                       \
      fg[h_][0] = *(const u16x8*)&bg_sm[CUR][nl][h_*32 + kg];                \
      fg[h_][1] = *(const u16x8*)&bg_sm[CUR][16 + nl][h_*32 + kg];           \
      fu[h_][0] = *(const u16x8*)&bu_sm[CUR][nl][h_*32 + kg];                \
      fu[h_][1] = *(const u16x8*)&bu_sm[CUR][16 + nl][h_*32 + kg];           \
  } }

#define GU_MFMA(AS)                                                          \
  { _Pragma("unroll") for (int h_ = 0; h_ < 2; ++h_) {                       \
      _Pragma("unroll") for (int mf = 0; mf < 4; ++mf) {                     \
        bf16x8 av = as_bf(AS[mf][h_]);                                       \
        accg[mf][0] = __builtin_amdgcn_mfma_f32_16x16x32_bf16(av, as_bfu(fg[h_][0]), accg[mf][0], 0,0,0); \
        accg[mf][1] = __builtin_amdgcn_mfma_f32_16x16x32_bf16(av, as_bfu(fg[h_][1]), accg[mf][1], 0,0,0); \
        accu[mf][0] = __builtin_amdgcn_mfma_f32_16x16x32_bf16(av, as_bfu(fu[h_][0]), accu[mf][0], 0,0,0); \
        accu[mf][1] = __builtin_amdgcn_mfma_f32_16x16x32_bf16(av, as_bfu(fu[h_][1]), accu[mf][1], 0,0,0); \
  } } }

#define GU_BODY(ACUR, ANXT, BSW, BSI, CUR, IT, DO_NEXT, DO_ISSUE, DO_BAR)    \
  { if (DO_NEXT)  GU_LOADA(ANXT, (IT)+1);                                    \
    if (DO_ISSUE) GU_LOADB(BSI, (IT)+2);                                     \
    u16x8 fg[2][2], fu[2][2];                                                \
    GU_READF(CUR);                                                           \
    if (DO_NEXT) { GU_WRITEB(BSW, (CUR)^1); }                                \
    GU_MFMA(ACUR);                                                           \
    if (DO_BAR) BAR();                                                       \
  }

__global__ __launch_bounds__(256, 2)
void gu_kernel(const u16* __restrict__ xb,
               const float* __restrict__ Wg,
               const float* __restrict__ Wu,
               u16* __restrict__ hbuf,
               const int* __restrict__ offs,
               const int* __restrict__ rtok) {
  __shared__ u16 bg_sm[2][32][68];
  __shared__ u16 bu_sm[2][32][68];

  int e  = blockIdx.z;
  int mt = blockIdx.y;
  int nt = blockIdx.x;
  int off0 = offs[e];
  int cnt  = offs[e+1] - off0;
  if (cnt <= 0 || mt * BM >= cnt) return;
  int p0 = off0 + mt * BM;
  int rmax = cnt - mt * BM - 1;
  int n0 = nt * 32;
  int tid = threadIdx.x;
  int lane = tid & 63, wv = tid >> 6;
  int kg = (lane >> 4) * 8;
  int nl = lane & 15;

  const u16* aptr[4];
#pragma unroll
  for (int mf = 0; mf < 4; ++mf) {
    int lrow = wv*64 + nl + mf*16;
    int tok = rtok[p0 + (lrow > rmax ? rmax : lrow)];
    aptr[mf] = xb + (size_t)tok * DH + kg;
  }

  // B staging geometry: thread = (gg, cc); loads 4 k-rows x 2 cols (float2)
  int cc = tid & 15;        // n-pair index (cols 2cc, 2cc+1)
  int gg = tid >> 4;        // k-group (rows 4gg..4gg+3)
  const float* gsrc = Wg + (size_t)e * DH * FH + (size_t)(4*gg) * FH + n0 + 2*cc;
  const float* usrc = Wu + (size_t)e * DH * FH + (size_t)(4*gg) * FH + n0 + 2*cc;

  f32x4 accg[4][2], accu[4][2];
#pragma unroll
  for (int mf = 0; mf < 4; ++mf)
#pragma unroll
    for (int nf = 0; nf < 2; ++nf) {
      accg[mf][nf] = f32x4{0.f,0.f,0.f,0.f};
      accu[mf][nf] = f32x4{0.f,0.f,0.f,0.f};
    }

  int4 A0[4][2], A1[4][2];
  float2 BAg[4], BAu[4], BBg[4], BBu[4];

  // prologue: B(0)->BA, A(0), write B(0) to buf0, issue B(1)->BB
  GU_LOADB(BA, 0);
  GU_LOADA(A0, 0);
  GU_WRITEB(BA, 0);
  GU_LOADB(BB, 1);
  BAR();

  for (int t = 0; t < 16; t += 2) {
    GU_BODY(A0, A1, BB, BA, 0, t,     1,            (t+2 < 16),   1);
    GU_BODY(A1, A0, BA, BB, 1, (t+1), (t+2 < 16),   (t+3 < 16),   (t+2 < 16));
  }

  // epilogue: h = silu(g)*u, bf16
#pragma unroll
  for (int mf = 0; mf < 4; ++mf) {
    int lr0 = wv*64 + (lane >> 4)*4 + mf*16;
#pragma unroll
    for (int nf = 0; nf < 2; ++nf) {
      int col = n0 + nf*16 + nl;
#pragma unroll
      for (int q = 0; q < 4; ++q) {
        int lrow = lr0 + q;
        if (lrow <= rmax) {
          float g = accg[mf][nf][q], u = accu[mf][nf][q];
          float s = g / (1.f + __expf(-g));
          hbuf[(size_t)(p0 + lrow) * FH + col] = f2bf(s * u);
        }
      }
    }
  }
}

// ---------------- 4. down projection, K-split=2 ----------------
#define DN_LOADA(AS, KT)                                                     \
  { _Pragma("unroll") for (int mf = 0; mf < 4; ++mf) {                       \
      AS[mf][0] = *(const int4*)(aptr[mf] + (KT)*64);                        \
      AS[mf][1] = *(const int4*)(aptr[mf] + (KT)*64 + 32);                   \
  } }

#define DN_LOADB(BS, KT)                                                     \
  { const float* dp_ = dsrc + (size_t)(KT)*64*DH;                            \
    _Pragma("unroll") for (int r_ = 0; r_ < 4; ++r_)                         \
      BS##d[r_] = *(const float2*)(dp_ + (size_t)r_*DH);                     \
  }

#define DN_WRITEB(BS, BUF)                                                   \
  { _Pragma("unroll") for (int j_ = 0; j_ < 2; ++j_) {                       \
      union { u16 s[4]; uint2 v; } pd_;                                      \
      _Pragma("unroll") for (int r_ = 0; r_ < 4; ++r_)                       \
        pd_.s[r_] = f2bf(j_ ? BS##d[r_].y : BS##d[r_].x);                    \
      *(uint2*)&bd_sm[BUF][2*cc + j_][4*gg] = pd_.v;                         \
  } }

#define DN_BODY(ACUR, ANXT, BSW, BSI, CUR, IT, DO_NEXT, DO_ISSUE, DO_BAR)    \
  { if (DO_NEXT)  DN_LOADA(ANXT, (IT)+1);                                    \
    if (DO_ISSUE) DN_LOADB(BSI, (IT)+2);                                     \
    u16x8 fd[2][2];                                                          \
    _Pragma("unroll") for (int h_ = 0; h_ < 2; ++h_) {                       \
      fd[h_][0] = *(const u16x8*)&bd_sm[CUR][nl][h_*32 + kg];                \
      fd[h_][1] = *(const u16x8*)&bd_sm[CUR][16 + nl][h_*32 + kg];           \
    }                                                                        \
    if (DO_NEXT) { DN_WRITEB(BSW, (CUR)^1); }                                \
    _Pragma("unroll") for (int h_ = 0; h_ < 2; ++h_) {                       \
      _Pragma("unroll") for (int mf = 0; mf < 4; ++mf) {                     \
        bf16x8 av = as_bf(ACUR[mf][h_]);                                     \
        acc[mf][0] = __builtin_amdgcn_mfma_f32_16x16x32_bf16(av, as_bfu(fd[h_][0]), acc[mf][0], 0,0,0); \
        acc[mf][1] = __builtin_amdgcn_mfma_f32_16x16x32_bf16(av, as_bfu(fd[h_][1]), acc[mf][1], 0,0,0); \
      } }                                                                    \
    if (DO_BAR) BAR();                                                       \
  }

__global__ __launch_bounds__(256, 2)
void dn_kernel(const u16* __restrict__ hb,
               const float* __restrict__ Wd,
               float* __restrict__ y,
               const int* __restrict__ offs) {
  __shared__ u16 bd_sm[2][32][68];

  int e  = blockIdx.z;
  int mt = blockIdx.y;
  int bx = blockIdx.x;
  int nt = bx & 31;
  int ks = bx >> 5;
  int kt0   = ks ? 1408 : 0;     // 22*64 ; 21*64 = 1344 ; total 2752
  int nIter = ks ? 21 : 22;
  int off0 = offs[e];
  int cnt  = offs[e+1] - off0;
  if (cnt <= 0 || mt * BM >= cnt) return;
  int p0 = off0 + mt * BM;
  int rmax = cnt - mt * BM - 1;
  int n0 = nt * 32;
  int tid = threadIdx.x;
  int lane = tid & 63, wv = tid >> 6;
  int kg = (lane >> 4) * 8;
  int nl = lane & 15;

  const u16* aptr[4];
#pragma unroll
  for (int mf = 0; mf < 4; ++mf) {
    int lrow = wv*64 + nl + mf*16;
    int arow = p0 + (lrow > rmax ? rmax : lrow);
    aptr[mf] = hb + (size_t)arow * FH + kt0 + kg;
  }

  int cc = tid & 15;
  int gg = tid >> 4;
  const float* dsrc = Wd + (size_t)e * FH * DH + (size_t)(kt0 + 4*gg) * DH + n0 + 2*cc;

  f32x4 acc[4][2];
#pragma unroll
  for (int mf = 0; mf < 4; ++mf)
#pragma unroll
    for (int nf = 0; nf < 2; ++nf)
      acc[mf][nf] = f32x4{0.f,0.f,0.f,0.f};

  int4 A0[4][2], A1[4][2];
  float2 BAd[4], BBd[4];

  DN_LOADB(BA, 0);
  DN_LOADA(A0, 0);
  DN_WRITEB(BA, 0);
  DN_LOADB(BB, 1);
  BAR();

  int it = 0;
  for (; it + 2 <= nIter; it += 2) {
    DN_BODY(A0, A1, BB, BA, 0, it,     (it+1 < nIter), (it+2 < nIter), 1);
    DN_BODY(A1, A0, BA, BB, 1, (it+1), (it+2 < nIter), (it+3 < nIter), (it+2 < nIter));
  }
  if (it < nIter) {   // odd tail (nIter=21): compute-only, parity even
    DN_BODY(A0, A1, BB, BA, 0, it, 0, 0, 0);
  }

  float* yout = y + (size_t)ks * 2048 * DH;
#pragma unroll
  for (int mf = 0; mf < 4; ++mf) {
    int lr0 = wv*64 + (lane >> 4)*4 + mf*16;
#pragma unroll
    for (int nf = 0; nf < 2; ++nf) {
      int col = n0 + nf*16 + nl;
#pragma unroll
      for (int q = 0; q < 4; ++q) {
        int lrow = lr0 + q;
        if (lrow <= rmax)
          yout[(size_t)(p0 + lrow) * DH + col] = acc[mf][nf][q];
      }
    }
  }
}

// ---------------- 5. combine ----------------
__global__ void combine_kernel(const float* __restrict__ y,
                               const float* __restrict__ tkw,
                               const int* __restrict__ posf,
                               float* __restrict__ out) {
  int t = blockIdx.x;
  int d = threadIdx.x;
  const float* y1 = y + (size_t)2048 * DH;
  int pa = posf[t*2], pb = posf[t*2+1];
  float wa = tkw[t*2], wb = tkw[t*2+1];
  f32x4 a0 = ((const f32x4*)(y  + (size_t)pa * DH))[d];
  f32x4 a1 = ((const f32x4*)(y1 + (size_t)pa * DH))[d];
  f32x4 b0 = ((const f32x4*)(y  + (size_t)pb * DH))[d];
  f32x4 b1 = ((const f32x4*)(y1 + (size_t)pb * DH))[d];
  f32x4 o;
#pragma unroll
  for (int i = 0; i < 4; ++i)
    o[i] = wa*(a0[i]+a1[i]) + wb*(b0[i]+b1[i]);
  ((f32x4*)(out + (size_t)t * DH))[d] = o;
}

extern "C" void kernel_launch(void* const* d_in, const int* in_sizes, int n_in,
                              void* d_out, int out_size, void* d_ws, size_t ws_size,
                              hipStream_t stream) {
  const float* x  = (const float*)d_in[0];
  const float* Ws = (const float*)d_in[1];
  const float* bs = (const float*)d_in[2];
  const float* Wg = (const float*)d_in[3];
  const float* Wu = (const float*)d_in[4];
  const float* Wd = (const float*)d_in[5];
  float* out = (float*)d_out;
  char* ws = (char*)d_ws;

  int*   tki  = (int*)  (ws + 0);
  float* tkw  = (float*)(ws + 8192);
  int*   offs = (int*)  (ws + 16384);
  int*   posf = (int*)  (ws + 20480);
  int*   rtok = (int*)  (ws + 28672);
  u16*   xb   = (u16*)  (ws + 36864);                 // 2 MB
  char*  base2 = ws + 36864 + 2097152;
  u16*   hbuf = (u16*)(base2);                        // 2048*2752 bf16 = 11.27 MB
  float* yws  = (float*)(base2 + 11272192);           // 2 * 2048*1024 f32 = 16 MB

  gate_kernel<<<256, 256, 0, stream>>>(x, Ws, bs, xb, tki, tkw);
  group_kernel<<<1, 256, 0, stream>>>(tki, offs, rtok, posf);
  gu_kernel<<<dim3(FH/32, 4, NE), 256, 0, stream>>>(xb, Wg, Wu, hbuf, offs, rtok);
  dn_kernel<<<dim3(64, 4, NE), 256, 0, stream>>>(hbuf, Wd, yws, offs);
  combine_kernel<<<NT, 256, 0, stream>>>(yws, tkw, posf, out);
}